// Round 1
// baseline (613.330 us; speedup 1.0000x reference)
//
#include <hip/hip_runtime.h>

#define D 64          // D_IN == D_OUT
#define D_EDGE 16
#define NEG 0.01f

typedef unsigned int  uint32;
typedef unsigned short ushort16;

__device__ __forceinline__ float leaky(float v) { return v > 0.f ? v : NEG * v; }

// fp32 -> bf16 (round-to-nearest-even), and back (exact)
__device__ __forceinline__ ushort16 f2bf(float f) {
    uint32 b = __float_as_uint(f);
    uint32 r = b + 0x7fffu + ((b >> 16) & 1u);
    return (ushort16)(r >> 16);
}
__device__ __forceinline__ float bf2f(ushort16 u) {
    return __uint_as_float(((uint32)u) << 16);
}

// ---------------- Kernel 1: per-node precompute (quarter-split) ----------------
//   4 threads per node; thread quarter q owns output channels [q*16, q*16+16).
//   xt[n] (bf16) = x[n] @ W2.T ; A[n] (bf16) = x[n] @ W1[:, :64].T
//   (r[] dropped: the x_r attn term is constant per dst segment and cancels
//    exactly in the softmax ratio.)
__global__ __launch_bounds__(256) void node_kernel(
    const float* __restrict__ x, const float* __restrict__ W1,
    const float* __restrict__ W2,
    ushort16* __restrict__ Abf, ushort16* __restrict__ xtb, int N_)
{
    __shared__ float w2s[64 * 64];
    __shared__ float w1s[64 * 64];
    for (int i = threadIdx.x; i < 64 * 64; i += 256) {
        w2s[i] = W2[i];
        int k = i >> 6, j = i & 63;
        w1s[i] = W1[k * 80 + j];
    }
    __syncthreads();

    const int lane = threadIdx.x & 63;
    const int q    = threadIdx.x >> 6;          // output quarter 0..3
    const int n    = blockIdx.x * 64 + lane;
    if (n >= N_) return;

    const float4* x4 = (const float4*)(x + (size_t)n * D);
    float4 xr[16];
#pragma unroll
    for (int i = 0; i < 16; i++) xr[i] = x4[i];

    const float4* w2s4 = (const float4*)w2s;
    const float4* w1s4 = (const float4*)w1s;

    uint32* Au = (uint32*)Abf;   // packed bf16x2, dword index = n*32 + k/2
    uint32* Xu = (uint32*)xtb;

    float a_prev = 0.f, b_prev = 0.f;
#pragma unroll
    for (int kk = 0; kk < 16; kk++) {
        const int k = q * 16 + kk;
        float a = 0.f, b = 0.f;
#pragma unroll
        for (int j = 0; j < 16; j++) {
            float4 w = w2s4[k * 16 + j];
            a += xr[j].x * w.x + xr[j].y * w.y + xr[j].z * w.z + xr[j].w * w.w;
            float4 u = w1s4[k * 16 + j];
            b += xr[j].x * u.x + xr[j].y * u.y + xr[j].z * u.z + xr[j].w * u.w;
        }
        if (kk & 1) {
            Xu[(size_t)n * 32 + (k >> 1)] = (uint32)f2bf(a_prev) | ((uint32)f2bf(a) << 16);
            Au[(size_t)n * 32 + (k >> 1)] = (uint32)f2bf(b_prev) | ((uint32)f2bf(b) << 16);
        } else {
            a_prev = a; b_prev = b;
        }
    }
}

// ---------------- CSR build: histogram + 3-kernel exclusive scan ----------------
__global__ __launch_bounds__(256) void hist_kernel(
    const int* __restrict__ dst, int* __restrict__ cnt, int E_)
{
    int i = blockIdx.x * 256 + threadIdx.x;
    if (i < E_) atomicAdd(cnt + dst[i], 1);
}

// block b reduces cnt[b*1024 .. b*1024+1023] -> part[b]
__global__ __launch_bounds__(256) void scan1(
    const int* __restrict__ cnt, int* __restrict__ part, int N_)
{
    __shared__ int sm[256];
    const int b = blockIdx.x, t = threadIdx.x;
    const int i0 = b * 1024 + t * 4;
    int s = 0;
    if (i0     < N_) s += cnt[i0];
    if (i0 + 1 < N_) s += cnt[i0 + 1];
    if (i0 + 2 < N_) s += cnt[i0 + 2];
    if (i0 + 3 < N_) s += cnt[i0 + 3];
    sm[t] = s; __syncthreads();
    for (int off = 128; off > 0; off >>= 1) {
        if (t < off) sm[t] += sm[t + off];
        __syncthreads();
    }
    if (t == 0) part[b] = sm[0];
}

// exclusive scan of block partials (nb <= 256; N=100000 -> nb=98)
__global__ __launch_bounds__(256) void scan2(int* __restrict__ part, int nb)
{
    __shared__ int sm[256];
    const int t = threadIdx.x;
    int v = (t < nb) ? part[t] : 0;
    sm[t] = v; __syncthreads();
    for (int off = 1; off < 256; off <<= 1) {
        int a = (t >= off) ? sm[t - off] : 0;
        __syncthreads();
        sm[t] += a;
        __syncthreads();
    }
    if (t < nb) part[t] = sm[t] - v;   // exclusive prefix of block sums
}

// block b writes exclusive prefix: rowst[i] = part[b] + scan_within_block
__global__ __launch_bounds__(256) void scan3(
    const int* __restrict__ cnt, const int* __restrict__ part,
    int* __restrict__ rowst, int N_)
{
    __shared__ int sm[256];
    const int b = blockIdx.x, t = threadIdx.x;
    const int i0 = b * 1024 + t * 4;
    int c0 = 0, c1 = 0, c2 = 0, c3 = 0;
    if (i0     < N_) c0 = cnt[i0];
    if (i0 + 1 < N_) c1 = cnt[i0 + 1];
    if (i0 + 2 < N_) c2 = cnt[i0 + 2];
    if (i0 + 3 < N_) c3 = cnt[i0 + 3];
    const int s = c0 + c1 + c2 + c3;
    sm[t] = s; __syncthreads();
    for (int off = 1; off < 256; off <<= 1) {
        int a = (t >= off) ? sm[t - off] : 0;
        __syncthreads();
        sm[t] += a;
        __syncthreads();
    }
    const int base = part[b] + (sm[t] - s);
    if (i0     < N_) rowst[i0]     = base;
    if (i0 + 1 < N_) rowst[i0 + 1] = base + c0;
    if (i0 + 2 < N_) rowst[i0 + 2] = base + c0 + c1;
    if (i0 + 3 < N_) rowst[i0 + 3] = base + c0 + c1 + c2;
}

// ---------------- Kernel 2: edge logits + CSR scatter (NO output atomics) ------
// Wave handles 2 edges (e0 = 2*pair, e1 = e0+1). Lane l: half = l>>5,
// k0 = (l&31)*2 — lane owns logit channels {k0,k0+1} of its half's edge.
// After the 32-lane butterfly, lanes 0/32 hold the full logit; they compute
// p = exp(v), claim a CSR slot via atomicAdd(rowst[dst]) and store {src, p}.
// (rowst[n] becomes the segment END after this kernel — classic bump trick.)
__global__ __launch_bounds__(256) void edge_kernel(
    const float* __restrict__ edge_attr, const int* __restrict__ src,
    const int* __restrict__ dst, const float* __restrict__ W1,
    const float* __restrict__ attn, const ushort16* __restrict__ Abf,
    int* __restrict__ rowpos, int2* __restrict__ SP, int E_, int chunk)
{
    const int lane = threadIdx.x & 63;
    const int half = lane >> 5;
    const int k0   = (lane & 31) * 2;

    const float4* w1p = (const float4*)(W1 + k0 * 80 + 64);
    float4 wa0 = w1p[0], wa1 = w1p[1], wa2 = w1p[2], wa3 = w1p[3];
    const float4* w1q = (const float4*)(W1 + (k0 + 1) * 80 + 64);
    float4 wb0 = w1q[0], wb1 = w1q[1], wb2 = w1q[2], wb3 = w1q[3];
    float ak0 = attn[k0], ak1 = attn[k0 + 1];

    const uint32* Au = (const uint32*)Abf;   // dword idx = s*32 + k0/2

    const int wave   = blockIdx.x * 4 + (threadIdx.x >> 6);
    const int npairs = E_ >> 1;
    int pr = wave * chunk;
    int pe = pr + chunk; if (pe > npairs) pe = npairs;

    for (; pr < pe; pr++) {
        const int e0 = pr * 2;
        int2 ss = *(const int2*)(src + e0);
        int2 dd = *(const int2*)(dst + e0);

        int s_h = half ? ss.y : ss.x;
        uint32 av = Au[(size_t)s_h * 32 + (lane & 31)];
        float a0 = bf2f((ushort16)(av & 0xffffu));
        float a1 = bf2f((ushort16)(av >> 16));

        const float4* eap = (const float4*)(edge_attr + (size_t)(e0 + half) * D_EDGE);
        float4 q0 = eap[0], q1 = eap[1], q2 = eap[2], q3 = eap[3];

        float g0 = q0.x*wa0.x + q0.y*wa0.y + q0.z*wa0.z + q0.w*wa0.w
                 + q1.x*wa1.x + q1.y*wa1.y + q1.z*wa1.z + q1.w*wa1.w
                 + q2.x*wa2.x + q2.y*wa2.y + q2.z*wa2.z + q2.w*wa2.w
                 + q3.x*wa3.x + q3.y*wa3.y + q3.z*wa3.z + q3.w*wa3.w;
        float g1 = q0.x*wb0.x + q0.y*wb0.y + q0.z*wb0.z + q0.w*wb0.w
                 + q1.x*wb1.x + q1.y*wb1.y + q1.z*wb1.z + q1.w*wb1.w
                 + q2.x*wb2.x + q2.y*wb2.y + q2.z*wb2.z + q2.w*wb2.w
                 + q3.x*wb3.x + q3.y*wb3.y + q3.z*wb3.z + q3.w*wb3.w;

        float v = leaky(a0 + g0) * ak0 + leaky(a1 + g1) * ak1;

        // butterfly within each 32-lane half: lane 0 / lane 32 get full sums
#pragma unroll
        for (int off = 16; off > 0; off >>= 1) v += __shfl_xor(v, off, 64);

        if ((lane & 31) == 0) {
            int d_h = half ? dd.y : dd.x;
            float pv = __expf(v);
            int pos = atomicAdd(rowpos + d_h, 1);
            SP[pos] = make_int2(s_h, __float_as_int(pv));
        }
    }

    // tail: odd E_ (not the case here, but stay correct)
    if (wave == 0 && (E_ & 1)) {
        int e = E_ - 1;
        int s = src[e], d = dst[e];
        uint32 av = Au[(size_t)s * 32 + (lane & 31)];
        float a0 = bf2f((ushort16)(av & 0xffffu));
        float a1 = bf2f((ushort16)(av >> 16));
        const float4* eap = (const float4*)(edge_attr + (size_t)e * D_EDGE);
        float4 q0 = eap[0], q1 = eap[1], q2 = eap[2], q3 = eap[3];
        float g0 = q0.x*wa0.x + q0.y*wa0.y + q0.z*wa0.z + q0.w*wa0.w
                 + q1.x*wa1.x + q1.y*wa1.y + q1.z*wa1.z + q1.w*wa1.w
                 + q2.x*wa2.x + q2.y*wa2.y + q2.z*wa2.z + q2.w*wa2.w
                 + q3.x*wa3.x + q3.y*wa3.y + q3.z*wa3.z + q3.w*wa3.w;
        float g1 = q0.x*wb0.x + q0.y*wb0.y + q0.z*wb0.z + q0.w*wb0.w
                 + q1.x*wb1.x + q1.y*wb1.y + q1.z*wb1.z + q1.w*wb1.w
                 + q2.x*wb2.x + q2.y*wb2.y + q2.z*wb2.z + q2.w*wb2.w
                 + q3.x*wb3.x + q3.y*wb3.y + q3.z*wb3.z + q3.w*wb3.w;
        float v = leaky(a0 + g0) * ak0 + leaky(a1 + g1) * ak1;
#pragma unroll
        for (int off = 16; off > 0; off >>= 1) v += __shfl_xor(v, off, 64);
        if (lane == 0) {
            int pos = atomicAdd(rowpos + d, 1);
            SP[pos] = make_int2(s, __float_as_int(__expf(v)));
        }
    }
}

// ---------------- Kernel 3: per-node CSR aggregation + normalize + bias --------
// One wave per node, lane = output channel. Walks the node's contiguous
// {src, p} segment, accumulates in registers, writes out exactly once.
__global__ __launch_bounds__(256) void agg_kernel(
    const ushort16* __restrict__ xtb, const int2* __restrict__ SP,
    const int* __restrict__ rowend, const float* __restrict__ bias,
    float* __restrict__ out, int N_)
{
    const int n    = blockIdx.x * 4 + (threadIdx.x >> 6);
    const int lane = threadIdx.x & 63;
    if (n >= N_) return;

    const int end   = rowend[n];
    const int start = n ? rowend[n - 1] : 0;

    float acc = 0.f, den = 0.f;
    int i = start;
    for (; i + 3 < end; i += 4) {
        int2 a = SP[i], b = SP[i + 1], c = SP[i + 2], d = SP[i + 3];
        float pa = __int_as_float(a.y), pb = __int_as_float(b.y);
        float pc = __int_as_float(c.y), pd = __int_as_float(d.y);
        float ma = bf2f(xtb[(size_t)a.x * D + lane]);
        float mb = bf2f(xtb[(size_t)b.x * D + lane]);
        float mc = bf2f(xtb[(size_t)c.x * D + lane]);
        float md = bf2f(xtb[(size_t)d.x * D + lane]);
        acc = fmaf(pa, ma, fmaf(pb, mb, fmaf(pc, mc, fmaf(pd, md, acc))));
        den += (pa + pb) + (pc + pd);
    }
    for (; i < end; i++) {
        int2 a = SP[i];
        float pa = __int_as_float(a.y);
        acc = fmaf(pa, bf2f(xtb[(size_t)a.x * D + lane]), acc);
        den += pa;
    }

    float sc = den > 0.f ? 1.f / den : 0.f;
    out[(size_t)n * D + lane] = fmaf(acc, sc, bias[lane]);
}

extern "C" void kernel_launch(void* const* d_in, const int* in_sizes, int n_in,
                              void* d_out, int out_size, void* d_ws, size_t ws_size,
                              hipStream_t stream)
{
    const float* x         = (const float*)d_in[0];
    const float* edge_attr = (const float*)d_in[1];
    const int*   src       = (const int*)d_in[2];
    const int*   dst       = (const int*)d_in[3];
    const float* W1        = (const float*)d_in[4];
    const float* W2        = (const float*)d_in[5];
    const float* attn      = (const float*)d_in[6];
    const float* bias      = (const float*)d_in[7];
    float* out = (float*)d_out;

    const int N_ = in_sizes[0] / D;   // 100000
    const int E_ = in_sizes[2];       // 1280000

    // workspace (~36.7 MB):
    //   Abf[N*64] bf16 | xtb[N*64] bf16 | SP[E] int2 | rowst[N] | cnt[N] | part[256]
    char* w = (char*)d_ws;
    ushort16* Abf  = (ushort16*)w;  w += (size_t)N_ * D * sizeof(ushort16);
    ushort16* xtb  = (ushort16*)w;  w += (size_t)N_ * D * sizeof(ushort16);
    int2*     SP   = (int2*)w;      w += (size_t)E_ * sizeof(int2);
    int*      rowst= (int*)w;       w += (size_t)N_ * sizeof(int);
    int*      cnt  = (int*)w;       w += (size_t)N_ * sizeof(int);
    int*      part = (int*)w;

    hipMemsetAsync(cnt, 0, (size_t)N_ * sizeof(int), stream);

    const int NB1 = (N_ + 1023) / 1024;   // 98 (<=256 supported by scan2)

    hist_kernel<<<(E_ + 255) / 256, 256, 0, stream>>>(dst, cnt, E_);
    scan1<<<NB1, 256, 0, stream>>>(cnt, part, N_);
    scan2<<<1, 256, 0, stream>>>(part, NB1);
    scan3<<<NB1, 256, 0, stream>>>(cnt, part, rowst, N_);

    node_kernel<<<(N_ + 63) / 64, 256, 0, stream>>>(x, W1, W2, Abf, xtb, N_);

    const int eBlocks = 8192;
    const int nwaves  = eBlocks * 4;
    const int npairs  = E_ >> 1;
    const int chunk   = (npairs + nwaves - 1) / nwaves;
    edge_kernel<<<eBlocks, 256, 0, stream>>>(edge_attr, src, dst, W1, attn,
                                             Abf, rowst, SP, E_, chunk);

    agg_kernel<<<(N_ + 3) / 4, 256, 0, stream>>>(xtb, SP, rowst, bias, out, N_);
}

// Round 2
// 409.796 us; speedup vs baseline: 1.4967x; 1.4967x over previous
//
#include <hip/hip_runtime.h>

#define D 64          // D_IN == D_OUT
#define D_EDGE 16
#define NEG 0.01f

typedef unsigned int  uint32;
typedef unsigned short ushort16;

// leaky = max(t, 0.01t): exact for both signs, 2 VALU ops
__device__ __forceinline__ float leaky(float v) { return fmaxf(v, NEG * v); }

// fp32 -> bf16 (round-to-nearest-even), and back (exact)
__device__ __forceinline__ ushort16 f2bf(float f) {
    uint32 b = __float_as_uint(f);
    uint32 r = b + 0x7fffu + ((b >> 16) & 1u);
    return (ushort16)(r >> 16);
}
__device__ __forceinline__ float bf2f(ushort16 u) {
    return __uint_as_float(((uint32)u) << 16);
}
__device__ __forceinline__ float bf_lo(uint32 w) { return __uint_as_float(w << 16); }
__device__ __forceinline__ float bf_hi(uint32 w) { return __uint_as_float(w & 0xffff0000u); }

// ---------------- Kernel 1: per-node precompute (quarter-split) ----------------
//   xt[n] (bf16) = x[n] @ W2.T ; A[n] (bf16) = x[n] @ W1[:, :64].T
//   (x_r attn term dropped: constant per dst segment, cancels in softmax.)
__global__ __launch_bounds__(256) void node_kernel(
    const float* __restrict__ x, const float* __restrict__ W1,
    const float* __restrict__ W2,
    ushort16* __restrict__ Abf, ushort16* __restrict__ xtb, int N_)
{
    __shared__ float w2s[64 * 64];
    __shared__ float w1s[64 * 64];
    for (int i = threadIdx.x; i < 64 * 64; i += 256) {
        w2s[i] = W2[i];
        int k = i >> 6, j = i & 63;
        w1s[i] = W1[k * 80 + j];
    }
    __syncthreads();

    const int lane = threadIdx.x & 63;
    const int q    = threadIdx.x >> 6;          // output quarter 0..3
    const int n    = blockIdx.x * 64 + lane;
    if (n >= N_) return;

    const float4* x4 = (const float4*)(x + (size_t)n * D);
    float4 xr[16];
#pragma unroll
    for (int i = 0; i < 16; i++) xr[i] = x4[i];

    const float4* w2s4 = (const float4*)w2s;
    const float4* w1s4 = (const float4*)w1s;

    uint32* Au = (uint32*)Abf;   // packed bf16x2, dword index = n*32 + k/2
    uint32* Xu = (uint32*)xtb;

    float a_prev = 0.f, b_prev = 0.f;
#pragma unroll
    for (int kk = 0; kk < 16; kk++) {
        const int k = q * 16 + kk;
        float a = 0.f, b = 0.f;
#pragma unroll
        for (int j = 0; j < 16; j++) {
            float4 w = w2s4[k * 16 + j];
            a += xr[j].x * w.x + xr[j].y * w.y + xr[j].z * w.z + xr[j].w * w.w;
            float4 u = w1s4[k * 16 + j];
            b += xr[j].x * u.x + xr[j].y * u.y + xr[j].z * u.z + xr[j].w * u.w;
        }
        if (kk & 1) {
            Xu[(size_t)n * 32 + (k >> 1)] = (uint32)f2bf(a_prev) | ((uint32)f2bf(a) << 16);
            Au[(size_t)n * 32 + (k >> 1)] = (uint32)f2bf(b_prev) | ((uint32)f2bf(b) << 16);
        } else {
            a_prev = a; b_prev = b;
        }
    }
}

// ---------------- CSR build: histogram + 3-kernel exclusive scan ----------------
__global__ __launch_bounds__(256) void hist_kernel(
    const int* __restrict__ dst, int* __restrict__ cnt, int E_)
{
    int i = blockIdx.x * 256 + threadIdx.x;
    if (i < E_) atomicAdd(cnt + dst[i], 1);
}

__global__ __launch_bounds__(256) void scan1(
    const int* __restrict__ cnt, int* __restrict__ part, int N_)
{
    __shared__ int sm[256];
    const int b = blockIdx.x, t = threadIdx.x;
    const int i0 = b * 1024 + t * 4;
    int s = 0;
    if (i0     < N_) s += cnt[i0];
    if (i0 + 1 < N_) s += cnt[i0 + 1];
    if (i0 + 2 < N_) s += cnt[i0 + 2];
    if (i0 + 3 < N_) s += cnt[i0 + 3];
    sm[t] = s; __syncthreads();
    for (int off = 128; off > 0; off >>= 1) {
        if (t < off) sm[t] += sm[t + off];
        __syncthreads();
    }
    if (t == 0) part[b] = sm[0];
}

__global__ __launch_bounds__(256) void scan2(int* __restrict__ part, int nb)
{
    __shared__ int sm[256];
    const int t = threadIdx.x;
    int v = (t < nb) ? part[t] : 0;
    sm[t] = v; __syncthreads();
    for (int off = 1; off < 256; off <<= 1) {
        int a = (t >= off) ? sm[t - off] : 0;
        __syncthreads();
        sm[t] += a;
        __syncthreads();
    }
    if (t < nb) part[t] = sm[t] - v;   // exclusive prefix of block sums
}

__global__ __launch_bounds__(256) void scan3(
    const int* __restrict__ cnt, const int* __restrict__ part,
    int* __restrict__ rowst, int N_)
{
    __shared__ int sm[256];
    const int b = blockIdx.x, t = threadIdx.x;
    const int i0 = b * 1024 + t * 4;
    int c0 = 0, c1 = 0, c2 = 0, c3 = 0;
    if (i0     < N_) c0 = cnt[i0];
    if (i0 + 1 < N_) c1 = cnt[i0 + 1];
    if (i0 + 2 < N_) c2 = cnt[i0 + 2];
    if (i0 + 3 < N_) c3 = cnt[i0 + 3];
    const int s = c0 + c1 + c2 + c3;
    sm[t] = s; __syncthreads();
    for (int off = 1; off < 256; off <<= 1) {
        int a = (t >= off) ? sm[t - off] : 0;
        __syncthreads();
        sm[t] += a;
        __syncthreads();
    }
    const int base = part[b] + (sm[t] - s);
    if (i0     < N_) rowst[i0]     = base;
    if (i0 + 1 < N_) rowst[i0 + 1] = base + c0;
    if (i0 + 2 < N_) rowst[i0 + 2] = base + c0 + c1;
    if (i0 + 3 < N_) rowst[i0 + 3] = base + c0 + c1 + c2;
}

// ---------------- Kernel 2: edge logits, ONE LANE PER EDGE ----------------
// Lane e computes its edge's full 64-channel logit serially:
//   v = sum_k leaky(A[src][k] + W1b[k] . ea[e]) * attn[k]
// 64 independent A-row gathers in flight per wave (vs 2 in the half-wave
// layout) -> gather latency fully hidden by ~2600 cy of VALU work.
// W1b rows + attn are wave-uniform loads -> scalar pipe (free vs VALU).
// No cross-lane reduction at all. Then p=exp(v), CSR slot bump, store {src,p}.
__global__ __launch_bounds__(256) void edge_kernel(
    const float* __restrict__ edge_attr, const int* __restrict__ src,
    const int* __restrict__ dst, const float* __restrict__ W1,
    const float* __restrict__ attn, const ushort16* __restrict__ Abf,
    int* __restrict__ rowpos, int2* __restrict__ SP, int E_)
{
    const int e = blockIdx.x * 256 + threadIdx.x;
    if (e >= E_) return;

    const int s = src[e];
    const int d = dst[e];

    // this lane's A row: 64 bf16 = 32 packed dwords (128 B), random gather
    uint32 Ad[32];
    {
        const uint4* Ap = (const uint4*)(Abf + (size_t)s * D);
#pragma unroll
        for (int i = 0; i < 8; i++) *(uint4*)(Ad + 4 * i) = Ap[i];
    }
    // this lane's edge_attr row: 16 f32 (64 B), dense across lanes
    float Ef[16];
    {
        const float4* Ep = (const float4*)(edge_attr + (size_t)e * D_EDGE);
#pragma unroll
        for (int i = 0; i < 4; i++) *(float4*)(Ef + 4 * i) = Ep[i];
    }

    float v = 0.f;
#pragma unroll
    for (int j = 0; j < 32; ++j) {          // packed dword j -> channels 2j, 2j+1
        // wave-uniform weight rows (16B-aligned): expect s_load
        const float4* w0 = (const float4*)(W1 + (2 * j) * 80 + 64);
        const float4* w1 = (const float4*)(W1 + (2 * j + 1) * 80 + 64);
        float4 p0 = w0[0], p1 = w0[1], p2 = w0[2], p3 = w0[3];
        float4 q0 = w1[0], q1 = w1[1], q2 = w1[2], q3 = w1[3];

        float g0 = bf_lo(Ad[j]);            // A[s][2j]
        float g1 = bf_hi(Ad[j]);            // A[s][2j+1]

        g0 = fmaf(Ef[ 0], p0.x, g0); g1 = fmaf(Ef[ 0], q0.x, g1);
        g0 = fmaf(Ef[ 1], p0.y, g0); g1 = fmaf(Ef[ 1], q0.y, g1);
        g0 = fmaf(Ef[ 2], p0.z, g0); g1 = fmaf(Ef[ 2], q0.z, g1);
        g0 = fmaf(Ef[ 3], p0.w, g0); g1 = fmaf(Ef[ 3], q0.w, g1);
        g0 = fmaf(Ef[ 4], p1.x, g0); g1 = fmaf(Ef[ 4], q1.x, g1);
        g0 = fmaf(Ef[ 5], p1.y, g0); g1 = fmaf(Ef[ 5], q1.y, g1);
        g0 = fmaf(Ef[ 6], p1.z, g0); g1 = fmaf(Ef[ 6], q1.z, g1);
        g0 = fmaf(Ef[ 7], p1.w, g0); g1 = fmaf(Ef[ 7], q1.w, g1);
        g0 = fmaf(Ef[ 8], p2.x, g0); g1 = fmaf(Ef[ 8], q2.x, g1);
        g0 = fmaf(Ef[ 9], p2.y, g0); g1 = fmaf(Ef[ 9], q2.y, g1);
        g0 = fmaf(Ef[10], p2.z, g0); g1 = fmaf(Ef[10], q2.z, g1);
        g0 = fmaf(Ef[11], p2.w, g0); g1 = fmaf(Ef[11], q2.w, g1);
        g0 = fmaf(Ef[12], p3.x, g0); g1 = fmaf(Ef[12], q3.x, g1);
        g0 = fmaf(Ef[13], p3.y, g0); g1 = fmaf(Ef[13], q3.y, g1);
        g0 = fmaf(Ef[14], p3.z, g0); g1 = fmaf(Ef[14], q3.z, g1);
        g0 = fmaf(Ef[15], p3.w, g0); g1 = fmaf(Ef[15], q3.w, g1);

        v = fmaf(leaky(g0), attn[2 * j],     v);
        v = fmaf(leaky(g1), attn[2 * j + 1], v);
    }

    const float p = __expf(v);
    const int pos = atomicAdd(rowpos + d, 1);
    SP[pos] = make_int2(s, __float_as_int(p));
}

// ---------------- Kernel 3: per-node CSR aggregation + normalize + bias --------
__global__ __launch_bounds__(256) void agg_kernel(
    const ushort16* __restrict__ xtb, const int2* __restrict__ SP,
    const int* __restrict__ rowend, const float* __restrict__ bias,
    float* __restrict__ out, int N_)
{
    const int n    = blockIdx.x * 4 + (threadIdx.x >> 6);
    const int lane = threadIdx.x & 63;
    if (n >= N_) return;

    const int end   = rowend[n];
    const int start = n ? rowend[n - 1] : 0;

    float acc = 0.f, den = 0.f;
    int i = start;
    for (; i + 3 < end; i += 4) {
        int2 a = SP[i], b = SP[i + 1], c = SP[i + 2], d = SP[i + 3];
        float pa = __int_as_float(a.y), pb = __int_as_float(b.y);
        float pc = __int_as_float(c.y), pd = __int_as_float(d.y);
        float ma = bf2f(xtb[(size_t)a.x * D + lane]);
        float mb = bf2f(xtb[(size_t)b.x * D + lane]);
        float mc = bf2f(xtb[(size_t)c.x * D + lane]);
        float md = bf2f(xtb[(size_t)d.x * D + lane]);
        acc = fmaf(pa, ma, fmaf(pb, mb, fmaf(pc, mc, fmaf(pd, md, acc))));
        den += (pa + pb) + (pc + pd);
    }
    for (; i < end; i++) {
        int2 a = SP[i];
        float pa = __int_as_float(a.y);
        acc = fmaf(pa, bf2f(xtb[(size_t)a.x * D + lane]), acc);
        den += pa;
    }

    float sc = den > 0.f ? 1.f / den : 0.f;
    out[(size_t)n * D + lane] = fmaf(acc, sc, bias[lane]);
}

extern "C" void kernel_launch(void* const* d_in, const int* in_sizes, int n_in,
                              void* d_out, int out_size, void* d_ws, size_t ws_size,
                              hipStream_t stream)
{
    const float* x         = (const float*)d_in[0];
    const float* edge_attr = (const float*)d_in[1];
    const int*   src       = (const int*)d_in[2];
    const int*   dst       = (const int*)d_in[3];
    const float* W1        = (const float*)d_in[4];
    const float* W2        = (const float*)d_in[5];
    const float* attn      = (const float*)d_in[6];
    const float* bias      = (const float*)d_in[7];
    float* out = (float*)d_out;

    const int N_ = in_sizes[0] / D;   // 100000
    const int E_ = in_sizes[2];       // 1280000

    // workspace (~36.7 MB):
    //   Abf[N*64] bf16 | xtb[N*64] bf16 | SP[E] int2 | rowst[N] | cnt[N] | part[256]
    char* w = (char*)d_ws;
    ushort16* Abf  = (ushort16*)w;  w += (size_t)N_ * D * sizeof(ushort16);
    ushort16* xtb  = (ushort16*)w;  w += (size_t)N_ * D * sizeof(ushort16);
    int2*     SP   = (int2*)w;      w += (size_t)E_ * sizeof(int2);
    int*      rowst= (int*)w;       w += (size_t)N_ * sizeof(int);
    int*      cnt  = (int*)w;       w += (size_t)N_ * sizeof(int);
    int*      part = (int*)w;

    hipMemsetAsync(cnt, 0, (size_t)N_ * sizeof(int), stream);

    const int NB1 = (N_ + 1023) / 1024;   // 98 (<=256 supported by scan2)

    hist_kernel<<<(E_ + 255) / 256, 256, 0, stream>>>(dst, cnt, E_);
    scan1<<<NB1, 256, 0, stream>>>(cnt, part, N_);
    scan2<<<1, 256, 0, stream>>>(part, NB1);
    scan3<<<NB1, 256, 0, stream>>>(cnt, part, rowst, N_);

    node_kernel<<<(N_ + 63) / 64, 256, 0, stream>>>(x, W1, W2, Abf, xtb, N_);

    edge_kernel<<<(E_ + 255) / 256, 256, 0, stream>>>(edge_attr, src, dst, W1,
                                                      attn, Abf, rowst, SP, E_);

    agg_kernel<<<(N_ + 3) / 4, 256, 0, stream>>>(xtb, SP, rowst, bias, out, N_);
}